// Round 1
// 180.017 us; speedup vs baseline: 1.0139x; 1.0139x over previous
//
#include <hip/hip_runtime.h>

// KANStressPredictor v7: barrier-free in-wave shuffle repartition.
// v6 post-mortem: 61.9us @ 30% HBM, VALU 25%, occ 39%, 1.18M LDS bank-conflict
// cycles -> latency-bound: one tile per block, 4 __syncthreads per tile, full
// vmcnt(0) drains; LDS transpose pays the LDS pipe twice. Nothing overlaps.
// v7: exploit mod-3 structure of AoS triplets at float4 granularity. Lane owns
// float4 g (r=g%3): its <=2 triplets need only prev-lane .w and next-lane .x
// (4 __shfl per float4), outputs likewise exchange 2 floats with neighbors.
// No LDS array, no barriers, coalesced float4 in/out, ILP-2 per thread.
// Wave-edge lanes (0/63) patch the missing neighbor floats with tiny global
// loads (L1/L2 hits; ~0.4% extra traffic). Every lane runs compute3 twice
// (1.5x min FLOPs) -- fine, VALU was 25% busy.
// Memory-bound: 201.3 MB total -> ~32us floor @ 6.3 TB/s.
// NOTE: __builtin_log2f/exp2f, NOT __log2f/__exp2f (glibc host-pass collision).

typedef unsigned int u32;

__device__ __forceinline__ void compute3(float s0, float s1, float s2,
                                         float ki0, float ki1,
                                         float& o0, float& o1, float& o2) {
    const float c00 = __builtin_fmaf(2.0f, s0, 1.0f);
    const float c11 = __builtin_fmaf(2.0f, s1, 1.0f);
    const float c01 = s2;
    const float det = c00 * c11 - c01 * c01;          // det(C) > 0 (SPD)
    const float l2det = __builtin_log2f(det);
    const float mean = 0.5f * (c00 + c11);
    const float diff = 0.5f * (c00 - c11);
    const float rad  = __builtin_sqrtf(__builtin_fmaf(diff, diff, c01 * c01));
    const float l2a = -0.16666666667f * l2det;        // log2(det^(-1/6))
    o0 = __builtin_exp2f(ki0 * __builtin_fmaf(0.5f, __builtin_log2f(mean - rad), l2a));
    o1 = __builtin_exp2f(ki0 * __builtin_fmaf(0.5f, __builtin_log2f(mean + rad), l2a));
    o2 = (0.34657359028f * l2det) * ki1;              // log(J)=0.5*ln2*l2det
}

// Process one float4 worth of the AoS stream.
// r = g%3 determines how the 4 floats split across triplets:
//  r==0: triplet (x,y,z) local; .w is o0 of next triplet (from lane+1).
//  r==1: P = (prev.w, x, y) -> [prev.w-slot, x, y]; S = (z, w, next.x) -> [z, w, next.x-slot].
//  r==2: triplet (y,z,w) local; .x is o2 of prev lane's S.
// Wave-edge lanes patch the missing neighbor floats from global memory.
__device__ __forceinline__ float4 process4(float4 v, u32 g, int l, u32 nf4,
                                           float ki0, float ki1,
                                           const float* __restrict__ gf) {
    const u32 r = g % 3u;
    float pw = __shfl_up(v.w, 1);      // prev lane's .w
    float nx = __shfl_down(v.x, 1);    // next lane's .x

    const bool last  = (l == 63) || (g == nf4 - 1u);  // no valid lane+1
    const bool first = (l == 0);                      // no valid lane-1
    float e0 = 0.0f, e1 = 0.0f;
    if (last) {
        if (r == 1u)      nx = gf[(size_t)4 * g + 4];
        else if (r == 0u) { e0 = gf[(size_t)4 * g + 4]; e1 = gf[(size_t)4 * g + 5]; }
    }
    if (first) {
        if (r == 1u)      pw = gf[(size_t)4 * g - 1];
        else if (r == 2u) { e0 = gf[(size_t)4 * g - 2]; e1 = gf[(size_t)4 * g - 1]; }
    }
    const bool fixN = last  && (r == 0u);  // compute next-triplet o0 locally
    const bool fixP = first && (r == 2u);  // compute prev-triplet o2 locally

    // primary triplet inputs
    const float pa = (r == 0u) ? v.x : (r == 1u) ? pw  : v.y;
    const float pb = (r == 0u) ? v.y : (r == 1u) ? v.x : v.z;
    const float pc = (r == 0u) ? v.z : (r == 1u) ? v.y : v.w;
    // secondary triplet inputs (meaningful for r==1 and the two edge fixes;
    // garbage (NaN-safe, no traps) otherwise)
    const float sa = fixN ? v.w : fixP ? e0  : v.z;
    const float sb = fixN ? e0  : fixP ? e1  : v.w;
    const float sc = fixN ? e1  : fixP ? v.x : nx;

    float Po0, Po1, Po2, So0, So1, So2;
    compute3(pa, pb, pc, ki0, ki1, Po0, Po1, Po2);
    compute3(sa, sb, sc, ki0, ki1, So0, So1, So2);

    const float nPo0 = __shfl_down(Po0, 1);  // next lane's P.o0 (for r==0 .w)
    const float pSo2 = __shfl_up(So2, 1);    // prev lane's S.o2 (for r==2 .x)

    float4 o;
    if (r == 0u) {
        o.x = Po0; o.y = Po1; o.z = Po2; o.w = last ? So0 : nPo0;
    } else if (r == 1u) {
        o.x = Po1; o.y = Po2; o.z = So0; o.w = So1;
    } else {
        o.x = fixP ? So2 : pSo2; o.y = Po0; o.z = Po1; o.w = Po2;
    }
    return o;
}

constexpr int TPB = 256;

__global__ __launch_bounds__(TPB) void kan_v7_shfl(
    const float* __restrict__ strain,
    const float* __restrict__ ki0p,
    const float* __restrict__ ki1p,
    float* __restrict__ out,
    int nfloat_i)
{
    const float ki0 = ki0p[0];
    const float ki1 = ki1p[0];
    const u32 nfloat = (u32)nfloat_i;
    const u32 nf4 = nfloat >> 2;
    const u32 t = threadIdx.x;
    const int l = (int)(t & 63u);
    const float4* __restrict__ in4  = (const float4*)strain;
    float4* __restrict__ out4 = (float4*)out;

    const u32 chunk = 2u * (u32)TPB;               // ILP-2: 512 float4/block-iter
    const u32 step = gridDim.x * chunk;
    for (u32 base = blockIdx.x * chunk; base < nf4; base += step) {
        const u32 g0 = base + t;
        const u32 g1 = base + (u32)TPB + t;
        const bool h0 = g0 < nf4;
        const bool h1 = g1 < nf4;
        float4 v0, v1;
        if (h0) v0 = in4[g0];
        if (h1) v1 = in4[g1];
        if (h0) out4[g0] = process4(v0, g0, l, nf4, ki0, ki1, strain);
        if (h1) out4[g1] = process4(v1, g1, l, nf4, ki0, ki1, strain);
    }

    // scalar tail: triplets not fully covered by the float4 region
    // (empty when nfloat % 4 == 0, e.g. the bench shape)
    const u32 ntrip = nfloat / 3u;
    const u32 t0 = (nf4 * 4u) / 3u;
    const u32 gs = gridDim.x * (u32)TPB;
    for (u32 e = t0 + blockIdx.x * (u32)TPB + t; e < ntrip; e += gs) {
        float o0, o1, o2;
        compute3(strain[3 * e], strain[3 * e + 1], strain[3 * e + 2],
                 ki0, ki1, o0, o1, o2);
        out[3 * e]     = o0;
        out[3 * e + 1] = o1;
        out[3 * e + 2] = o2;
    }
}

extern "C" void kernel_launch(void* const* d_in, const int* in_sizes, int n_in,
                              void* d_out, int out_size, void* d_ws, size_t ws_size,
                              hipStream_t stream) {
    const float* strain = (const float*)d_in[0];
    const float* ki0p   = (const float*)d_in[1];
    const float* ki1p   = (const float*)d_in[2];
    float* out = (float*)d_out;

    const int nfloat = in_sizes[0];
    const u32 nf4 = ((u32)nfloat) >> 2;
    u32 blocks = (nf4 + 511u) / 512u;              // chunks of 512 float4
    if (blocks > 4096u) blocks = 4096u;            // 16 blocks/CU, grid-stride
    if (blocks < 1u) blocks = 1u;

    kan_v7_shfl<<<(int)blocks, TPB, 0, stream>>>(strain, ki0p, ki1p, out, nfloat);
}

// Round 3
// 179.497 us; speedup vs baseline: 1.0168x; 1.0029x over previous
//
#include <hip/hip_runtime.h>

// KANStressPredictor v9: v8 + wave-level LDS fences (race fix).
// v8 post-mortem: NaN. Cause: lane l's strided ds_read S[3l+j] consumes other
// lanes' linear ds_writes; per-thread IR sees no dependency -> compiler free
// to reorder ds_read above ds_write (rule #18 class). HW DS pipe is in-order
// per wave; the COMPILER needed the fence. Fix: asm "s_waitcnt lgkmcnt(0)"
// + "memory" clobber at the 3 phase transitions. lgkmcnt tracks DS only --
// global prefetch is vmcnt -> HBM latency still overlaps compute (the whole
// point vs v6's __syncthreads + vmcnt(0) drains).
// Structure (unchanged from v8): each lane owns 3 consecutive float4 = exactly
// 4 triplets (768-float4 block chunk is triplet-aligned): 1.33 compute3/float4,
// no shuffles, no edge cases. Coalescing via 3KB per-WAVE LDS slab:
// coalesced glb load -> linear ds_write -> strided(48B) ds_read_b128 ->
// compute -> strided write -> linear read -> coalesced store. Zero s_barrier.
// Algebra: log2(lam1) = log2(det) - log2(lam0) -> 5 trans/triplet (was 6).
// Net 12 -> 6.7 trans/float4 vs v7 (-44% VALU). Cross-iter register prefetch.
// Memory-bound floor: 201.3 MB -> ~32us @ 6.3 TB/s (less w/ L3 read hits).
// NOTE: __builtin_log2f/exp2f, NOT __log2f/__exp2f (glibc host-pass collision).

typedef unsigned int u32;

// Wave-level LDS fence: compiler barrier (memory clobber) + wait for all DS
// writes to commit. Does NOT wait on vmcnt -> global prefetch stays in flight.
#define WAVE_LDS_FENCE() asm volatile("s_waitcnt lgkmcnt(0)" ::: "memory")

__device__ __forceinline__ void compute3(float s0, float s1, float s2,
                                         float ki0, float ki1,
                                         float& o0, float& o1, float& o2) {
    const float c00 = __builtin_fmaf(2.0f, s0, 1.0f);
    const float c11 = __builtin_fmaf(2.0f, s1, 1.0f);
    const float c01 = s2;
    const float det = c00 * c11 - c01 * c01;          // det(C) > 0 (SPD)
    const float l2det = __builtin_log2f(det);
    const float mean = 0.5f * (c00 + c11);
    const float diff = 0.5f * (c00 - c11);
    const float rad  = __builtin_sqrtf(__builtin_fmaf(diff, diff, c01 * c01));
    const float l2lam0 = __builtin_log2f(mean - rad); // no cancellation: mean>=1, rad<=~0.28
    const float l2a = -0.16666666667f * l2det;        // log2(det^(-1/6))
    o0 = __builtin_exp2f(ki0 * __builtin_fmaf(0.5f, l2lam0, l2a));
    // log2(lam1) = l2det - l2lam0  ->  arg = ki0*(l2det/3 - 0.5*l2lam0)
    o1 = __builtin_exp2f(ki0 * __builtin_fmaf(-0.5f, l2lam0,
                                  __builtin_fmaf(0.5f, l2det, l2a)));
    o2 = (0.34657359028f * l2det) * ki1;              // log(J)=0.5*ln2*l2det
}

constexpr int TPB = 256;
constexpr int WPB = TPB / 64;          // 4 waves/block
constexpr int WCH = 192;               // float4 per wave-chunk (256 triplets)
constexpr int BCH = WPB * WCH;         // 768 float4 per block-chunk (1024 triplets)

__global__ __launch_bounds__(TPB) void kan_v9_wavelds(
    const float* __restrict__ strain,
    const float* __restrict__ ki0p,
    const float* __restrict__ ki1p,
    float* __restrict__ out,
    int nfloat_i)
{
    __shared__ float4 slab[WPB][WCH];  // 12,288 B -> LDS never the occupancy cap
    const float ki0 = ki0p[0];
    const float ki1 = ki1p[0];
    const u32 nfloat = (u32)nfloat_i;
    const u32 nf4 = nfloat >> 2;
    const u32 nchunk = nf4 / BCH;
    const u32 t = threadIdx.x;
    const u32 w = t >> 6;
    const u32 l = t & 63u;
    float4* S = slab[w];               // wave-private slab: no cross-wave hazard
    const float4* __restrict__ in4 = (const float4*)strain;
    float4* __restrict__ out4 = (float4*)out;
    const u32 G = gridDim.x;

    u32 c = blockIdx.x;
    float4 p0, p1, p2;
    if (c < nchunk) {                  // prologue prefetch
        const float4* b = in4 + (size_t)c * BCH + w * WCH;
        p0 = b[l]; p1 = b[l + 64]; p2 = b[l + 128];
    }
    while (c < nchunk) {
        // stage current chunk into wave slab (linear, conflict-free)
        S[l] = p0; S[l + 64] = p1; S[l + 128] = p2;

        // prefetch next chunk (global_load -> vmcnt; overlaps everything below)
        const u32 cn = c + G;
        if (cn < nchunk) {
            const float4* b = in4 + (size_t)cn * BCH + w * WCH;
            p0 = b[l]; p1 = b[l + 64]; p2 = b[l + 128];
        }

        WAVE_LDS_FENCE();  // stage writes visible before cross-lane reads

        // strided read: lane owns float4s [3l, 3l+3) = 4 whole triplets
        const float4 a  = S[3u * l];
        const float4 b4 = S[3u * l + 1];
        const float4 c4 = S[3u * l + 2];

        float o0,o1,o2,o3,o4,o5,o6,o7,o8,o9,oa,ob;
        compute3(a.x,  a.y,  a.z,  ki0, ki1, o0, o1, o2);
        compute3(a.w,  b4.x, b4.y, ki0, ki1, o3, o4, o5);
        compute3(b4.z, b4.w, c4.x, ki0, ki1, o6, o7, o8);
        compute3(c4.y, c4.z, c4.w, ki0, ki1, o9, oa, ob);

        // strided write-back
        S[3u * l]     = make_float4(o0, o1, o2, o3);
        S[3u * l + 1] = make_float4(o4, o5, o6, o7);
        S[3u * l + 2] = make_float4(o8, o9, oa, ob);

        WAVE_LDS_FENCE();  // strided writes visible before cross-lane linear reads

        // linear read + coalesced store
        const float4 q0 = S[l], q1 = S[l + 64], q2 = S[l + 128];
        float4* ob4 = out4 + (size_t)c * BCH + w * WCH;
        ob4[l] = q0; ob4[l + 64] = q1; ob4[l + 128] = q2;

        WAVE_LDS_FENCE();  // linear reads done before next-iter staging overwrite (WAR)

        c = cn;
    }

    // tail: triplets past the last full chunk (empty for the bench shape)
    const u32 ntrip = nfloat / 3u;
    const u32 t0 = nchunk * (BCH * 4u / 3u);   // 1024 triplets per chunk
    const u32 gs = G * (u32)TPB;
    for (u32 e = t0 + blockIdx.x * (u32)TPB + t; e < ntrip; e += gs) {
        float x0, x1, x2;
        compute3(strain[3 * e], strain[3 * e + 1], strain[3 * e + 2],
                 ki0, ki1, x0, x1, x2);
        out[3 * e]     = x0;
        out[3 * e + 1] = x1;
        out[3 * e + 2] = x2;
    }
}

extern "C" void kernel_launch(void* const* d_in, const int* in_sizes, int n_in,
                              void* d_out, int out_size, void* d_ws, size_t ws_size,
                              hipStream_t stream) {
    const float* strain = (const float*)d_in[0];
    const float* ki0p   = (const float*)d_in[1];
    const float* ki1p   = (const float*)d_in[2];
    float* out = (float*)d_out;

    const int nfloat = in_sizes[0];
    const u32 nf4 = ((u32)nfloat) >> 2;
    u32 blocks = nf4 / (u32)BCH;           // one chunk per block-iteration
    if (blocks > 2048u) blocks = 2048u;    // 8 blocks/CU resident, grid-stride
    if (blocks < 1u) blocks = 1u;

    kan_v9_wavelds<<<(int)blocks, TPB, 0, stream>>>(strain, ki0p, ki1p, out, nfloat);
}